// Round 10
// baseline (390.900 us; speedup 1.0000x reference)
//
#include <hip/hip_runtime.h>

#define N_PTS 16384
#define DIMS  128
#define NQ    16384
#define NV    64
#define KT2   256   // [h1 | h2] layout, 128 cols each
#define BK    64
#define BM    128
#define BN    128
#define CHUNK_NT 16                // ntiles per block
#define CHUNK_N  (BN * CHUNK_NT)   // 2048 points per block
#define NCHUNK   (N_PTS / CHUNK_N) // 8

typedef __attribute__((ext_vector_type(8))) _Float16 half8;
typedef __attribute__((ext_vector_type(4))) _Float16 half4;
typedef __attribute__((ext_vector_type(4))) float    f32x4;

// ---- fused preprocessing: split both inputs to [h1|h2], p_sq for points, keys init ----
#define QBLOCKS (NQ * DIMS / 1024)
#define PBLOCKS (N_PTS * DIMS / 1024)
__global__ __launch_bounds__(256) void split_fused(const float* __restrict__ q,
                                                   const float* __restrict__ pts,
                                                   _Float16* __restrict__ Aq,
                                                   _Float16* __restrict__ Bp,
                                                   float* __restrict__ p_sq,
                                                   unsigned long long* __restrict__ keys) {
    int t = blockIdx.x * 256 + threadIdx.x;
    if (t < NQ) keys[t] = ~0ull;
    const float* src;
    _Float16* dst;
    int t2;
    bool is_p = blockIdx.x >= QBLOCKS;
    if (is_p) { t2 = t - QBLOCKS * 256; src = pts; dst = Bp; }
    else      { t2 = t;                 src = q;   dst = Aq; }
    int idx4 = t2 * 4;
    int r = idx4 >> 7, c = idx4 & 127;
    float4 x = *(const float4*)(src + idx4);
    float xs[4] = {x.x, x.y, x.z, x.w};
    half4 h1, h2;
    float s = 0.f;
#pragma unroll
    for (int j = 0; j < 4; ++j) {
        _Float16 a = (_Float16)xs[j];
        h1[j] = a;
        h2[j] = (_Float16)(xs[j] - (float)a);
        s += xs[j] * xs[j];
    }
    _Float16* o = dst + (size_t)r * KT2 + c;
    *(half4*)o = h1; *(half4*)(o + 128) = h2;
    if (is_p) {
#pragma unroll
        for (int off = 1; off < 32; off <<= 1) s += __shfl_xor(s, off, 64);
        if ((threadIdx.x & 31) == 0) p_sq[r] = s;
    }
}

__device__ __forceinline__ unsigned int f2sortable(float f) {
    unsigned int b = __float_as_uint(f);
    return (b & 0x80000000u) ? ~b : (b | 0x80000000u);
}

__device__ __forceinline__ void gload16(const _Float16* g, const _Float16* l) {
    __builtin_amdgcn_global_load_lds((const __attribute__((address_space(1))) void*)g,
                                     (__attribute__((address_space(3))) void*)l, 16, 0, 0);
}

// -------- main: A fully in registers (af[4]); B-only LDS, 2-phase segments, 3 barriers/ntile --------
__global__ __launch_bounds__(256, 2) void nn_mfma(const _Float16* __restrict__ A,   // [NQ][256]
                                                  const _Float16* __restrict__ B,   // [N_PTS][256]
                                                  const float* __restrict__ p_sq,
                                                  unsigned long long* __restrict__ keys) {
    __shared__ _Float16 Bs[2][2][BN * BK];   // [half][slot] : 4 x 16 KB = 64 KB

    const int bid   = blockIdx.x;
    const int mtile = bid >> 3;
    const int chunk = bid & 7;
    const int nbase = chunk * CHUNK_N;

    const int tid = threadIdx.x;
    const int w   = tid >> 6;
    const int l   = tid & 63;
    const int wq  = w >> 1;               // wave quadrant rows wq*64, cols wp*64
    const int wp  = w & 1;
    const int q16 = l >> 4;
    const int c16 = l & 15;

    const int srow = l >> 3;
    const int gch  = (l & 7) ^ (srow & 7);   // proven 0-conflict staging swizzle

    const _Float16* __restrict__ pa = A + (size_t)mtile * BM * KT2;
    const _Float16* __restrict__ pb = B + (size_t)nbase * KT2;

    int blane[4], ldsoff[4];
#pragma unroll
    for (int i = 0; i < 4; ++i) {
        blane[i]  = (w * 32 + i * 8 + srow) * KT2 + gch * 8;   // phase-invariant
        ldsoff[i] = (w * 32 + i * 8) * BK;
    }

    auto stageTo = [&](const _Float16* gbase, _Float16* lbase) {
#pragma unroll
        for (int i = 0; i < 4; ++i)
            gload16(gbase + blane[i], lbase + ldsoff[i]);
    };

    // prologue: stage Bh1_0 of nt=0 into half0/slot0
    stageTo(pb, &Bs[0][0][0]);

    // A fragments -> registers, once per block.
    // af[s][ks][mi]: s = 0:h1 slice0, 1:h1 slice1, 2:h2 slice0, 3:h2 slice1
    half8 af[4][2][4];
#pragma unroll
    for (int s = 0; s < 4; ++s)
#pragma unroll
        for (int ks = 0; ks < 2; ++ks)
#pragma unroll
            for (int mi = 0; mi < 4; ++mi) {
                int row = wq * 64 + mi * 16 + c16;
                af[s][ks][mi] = *(const half8*)(pa + (size_t)row * KT2 + s * 64 + ks * 32 + q16 * 8);
            }

    float    best[4][4];
    unsigned bpak[4][2];
#pragma unroll
    for (int mi = 0; mi < 4; ++mi) {
        best[mi][0] = best[mi][1] = best[mi][2] = best[mi][3] = 3.4e38f;
        bpak[mi][0] = bpak[mi][1] = 0;
    }

    f32x4 acc[4][4] = {};

    // segment with TWO products sharing one B slice (b read once per ks)
    auto segDual = [&](const _Float16* bs, const half8 (&a0)[2][4], const half8 (&a1)[2][4]) {
#pragma unroll
        for (int ks = 0; ks < 2; ++ks) {
            int slot8 = ((ks * 4 + q16) ^ (c16 & 7)) * 8;
            half8 b[4];
#pragma unroll
            for (int ni = 0; ni < 4; ++ni)
                b[ni] = *(const half8*)(bs + (wp * 64 + ni * 16 + c16) * BK + slot8);
#pragma unroll
            for (int mi = 0; mi < 4; ++mi)
#pragma unroll
                for (int ni = 0; ni < 4; ++ni)
                    acc[mi][ni] = __builtin_amdgcn_mfma_f32_16x16x32_f16(a0[ks][mi], b[ni], acc[mi][ni], 0, 0, 0);
#pragma unroll
            for (int mi = 0; mi < 4; ++mi)
#pragma unroll
                for (int ni = 0; ni < 4; ++ni)
                    acc[mi][ni] = __builtin_amdgcn_mfma_f32_16x16x32_f16(a1[ks][mi], b[ni], acc[mi][ni], 0, 0, 0);
        }
    };
    // single product on one B slice
    auto segOne = [&](const _Float16* bs, const half8 (&a0)[2][4]) {
#pragma unroll
        for (int ks = 0; ks < 2; ++ks) {
            int slot8 = ((ks * 4 + q16) ^ (c16 & 7)) * 8;
            half8 b[4];
#pragma unroll
            for (int ni = 0; ni < 4; ++ni)
                b[ni] = *(const half8*)(bs + (wp * 64 + ni * 16 + c16) * BK + slot8);
#pragma unroll
            for (int mi = 0; mi < 4; ++mi)
#pragma unroll
                for (int ni = 0; ni < 4; ++ni)
                    acc[mi][ni] = __builtin_amdgcn_mfma_f32_16x16x32_f16(a0[ks][mi], b[ni], acc[mi][ni], 0, 0, 0);
        }
    };

#pragma unroll 1
    for (int nt = 0; nt < CHUNK_NT; ++nt) {
        const _Float16* pbn = pb + (size_t)nt * BN * KT2;
        const int h0 = (nt * 3) & 1;          // half used by seg0 (and seg2); seg1 uses h0^1

        float psq[4];
#pragma unroll
        for (int ni = 0; ni < 4; ++ni)
            psq[ni] = p_sq[nbase + nt * BN + wp * 64 + ni * 16 + c16];

        // seg0: Bh1_0 @ Bs[h0][0]; products af[0] (h1_0), af[2] (h2_0)
        __syncthreads();                       // drains stage of Bh1_0
        stageTo(pbn + 64, &Bs[h0 ^ 1][0][0]);  // stage Bh1_1 for seg1
        segDual(&Bs[h0][0][0], af[0], af[2]);

        // seg1: Bh1_1 @ Bs[h0^1][0]; products af[1] (h1_1), af[3] (h2_1)
        __syncthreads();
        stageTo(pbn + 128, &Bs[h0][0][0]);     // stage Bh2_0 for seg2
        stageTo(pbn + 192, &Bs[h0][1][0]);     // stage Bh2_1 for seg2
        segDual(&Bs[h0 ^ 1][0][0], af[1], af[3]);

        // seg2: Bh2_0 @ Bs[h0][0] with af[0]; Bh2_1 @ Bs[h0][1] with af[1]
        __syncthreads();
        if (nt + 1 < CHUNK_NT)
            stageTo(pbn + BN * KT2, &Bs[h0 ^ 1][0][0]);   // stage next ntile's Bh1_0
        segOne(&Bs[h0][0][0], af[0]);
        segOne(&Bs[h0][1][0], af[1]);

        // per-ntile argmin update (registers only; candidates ascend in idx => strict <)
#pragma unroll
        for (int mi = 0; mi < 4; ++mi)
#pragma unroll
            for (int reg = 0; reg < 4; ++reg) {
                float s0 = psq[0] - 2.0f * acc[mi][0][reg];
                float s1 = psq[1] - 2.0f * acc[mi][1][reg];
                float s2 = psq[2] - 2.0f * acc[mi][2][reg];
                float s3 = psq[3] - 2.0f * acc[mi][3][reg];
                float bv = s0; int bn2 = 0;
                if (s1 < bv) { bv = s1; bn2 = 1; }
                if (s2 < bv) { bv = s2; bn2 = 2; }
                if (s3 < bv) { bv = s3; bn2 = 3; }
                bool take = bv < best[mi][reg];
                unsigned lidx = (unsigned)(nt * BN + wp * 64 + (bn2 << 4) + c16);
                unsigned sh = (reg & 1) * 16;
                unsigned cur = bpak[mi][reg >> 1];
                unsigned nw  = (cur & ~(0xFFFFu << sh)) | (lidx << sh);
                best[mi][reg]      = take ? bv : best[mi][reg];
                bpak[mi][reg >> 1] = take ? nw : cur;
            }
#pragma unroll
        for (int mi = 0; mi < 4; ++mi)
#pragma unroll
            for (int ni = 0; ni < 4; ++ni)
                acc[mi][ni] = (f32x4)(0.f);
    }

    // final: butterfly across c16 lanes, one atomic per row
#pragma unroll
    for (int mi = 0; mi < 4; ++mi)
#pragma unroll
        for (int reg = 0; reg < 4; ++reg) {
            float    bv   = best[mi][reg];
            unsigned lidx = (bpak[mi][reg >> 1] >> ((reg & 1) * 16)) & 0xFFFFu;
#pragma unroll
            for (int off = 1; off < 16; off <<= 1) {
                float    ov = __shfl_xor(bv, off, 64);
                unsigned oi = __shfl_xor((int)lidx, off, 64);
                if (ov < bv || (ov == bv && oi < lidx)) { bv = ov; lidx = oi; }
            }
            if (c16 == 0) {
                int row = mtile * BM + wq * 64 + mi * 16 + q16 * 4 + reg;
                unsigned long long key =
                    ((unsigned long long)f2sortable(bv) << 32) | (unsigned)(nbase + lidx);
                atomicMin(&keys[row], key);
            }
        }
}

// ---------------- gather ----------------
__global__ __launch_bounds__(256) void gather_kernel(const unsigned long long* __restrict__ keys,
                                                     const float* __restrict__ values,
                                                     float* __restrict__ out) {
    int tid = threadIdx.x;
    int q = blockIdx.x * 16 + (tid >> 4);
    int c = tid & 15;
    int idx = (int)(keys[q] & 0xFFFFFFFFull);
    const float4* src = (const float4*)(values + (size_t)idx * NV);
    float4*       dst = (float4*)(out + (size_t)q * NV);
    dst[c] = src[c];
}

// ================= fallback (round-1 fp32 LDS kernel) =================
#define QT 64
#define PT 64
#define LSTRIDE 132
__global__ __launch_bounds__(256, 2) void nn_kernel(const float* __restrict__ points,
                                                    const float* __restrict__ values,
                                                    const float* __restrict__ pointsq,
                                                    const float* __restrict__ p_sq,
                                                    float* __restrict__ out) {
    __shared__ float lq[QT * LSTRIDE];
    __shared__ float lp[PT * LSTRIDE];
    __shared__ float lps[PT];
    __shared__ float red_val[QT][16];
    __shared__ int   red_idx[QT][16];
    __shared__ int   nn_idx[QT];

    const int tid = threadIdx.x;
    const int tx = tid & 15, ty = tid >> 4;
    const int qbase = blockIdx.x * QT;
    {
        int ql = tid >> 2, quad = tid & 3;
        const float4* src = (const float4*)(pointsq + (size_t)(qbase + ql) * DIMS);
#pragma unroll
        for (int j = 0; j < 8; ++j)
            *(float4*)(lq + ql * LSTRIDE + (quad + 4 * j) * 4) = src[quad + 4 * j];
    }
    float minv[4]; int mini[4];
#pragma unroll
    for (int qi = 0; qi < 4; ++qi) { minv[qi] = 3.4e38f; mini[qi] = 0; }
    for (int tile = 0; tile < N_PTS / PT; ++tile) {
        __syncthreads();
        {
            int pl = tid >> 2, quad = tid & 3;
            const float4* src = (const float4*)(points + (size_t)(tile * PT + pl) * DIMS);
#pragma unroll
            for (int j = 0; j < 8; ++j)
                *(float4*)(lp + pl * LSTRIDE + (quad + 4 * j) * 4) = src[quad + 4 * j];
            if (tid < PT) lps[tid] = p_sq[tile * PT + tid];
        }
        __syncthreads();
        float accl[4][4];
#pragma unroll
        for (int qi = 0; qi < 4; ++qi)
#pragma unroll
            for (int pi = 0; pi < 4; ++pi) accl[qi][pi] = 0.f;
        for (int kc = 0; kc < DIMS / 4; ++kc) {
            float4 aq[4], ap[4];
#pragma unroll
            for (int qi = 0; qi < 4; ++qi) aq[qi] = *(const float4*)(lq + (ty + 16 * qi) * LSTRIDE + kc * 4);
#pragma unroll
            for (int pi = 0; pi < 4; ++pi) ap[pi] = *(const float4*)(lp + (tx + 16 * pi) * LSTRIDE + kc * 4);
#pragma unroll
            for (int qi = 0; qi < 4; ++qi)
#pragma unroll
                for (int pi = 0; pi < 4; ++pi) {
                    accl[qi][pi] += aq[qi].x * ap[pi].x; accl[qi][pi] += aq[qi].y * ap[pi].y;
                    accl[qi][pi] += aq[qi].z * ap[pi].z; accl[qi][pi] += aq[qi].w * ap[pi].w;
                }
        }
#pragma unroll
        for (int qi = 0; qi < 4; ++qi)
#pragma unroll
            for (int pi = 0; pi < 4; ++pi) {
                float score = lps[tx + 16 * pi] - 2.f * accl[qi][pi];
                int idx = tile * PT + tx + 16 * pi;
                if (score < minv[qi]) { minv[qi] = score; mini[qi] = idx; }
            }
    }
    __syncthreads();
#pragma unroll
    for (int qi = 0; qi < 4; ++qi) { red_val[ty + 16 * qi][tx] = minv[qi]; red_idx[ty + 16 * qi][tx] = mini[qi]; }
    __syncthreads();
    if (tid < QT) {
        float bv = red_val[tid][0]; int bi = red_idx[tid][0];
#pragma unroll
        for (int t = 1; t < 16; ++t) {
            float v = red_val[tid][t]; int i = red_idx[tid][t];
            if (v < bv || (v == bv && i < bi)) { bv = v; bi = i; }
        }
        nn_idx[tid] = bi;
    }
    __syncthreads();
    {
        int ql = tid >> 2, quad = tid & 3;
        const float4* src = (const float4*)(values + (size_t)nn_idx[ql] * NV);
        float4* dst = (float4*)(out + (size_t)(qbase + ql) * NV);
#pragma unroll
        for (int j = 0; j < 4; ++j) dst[quad * 4 + j] = src[quad * 4 + j];
    }
}

__global__ __launch_bounds__(256) void psq_kernel(const float* __restrict__ points,
                                                  float* __restrict__ p_sq) {
    int row  = blockIdx.x * 4 + (threadIdx.x >> 6);
    int lane = threadIdx.x & 63;
    float2 v = *(const float2*)(points + row * DIMS + lane * 2);
    float s = v.x * v.x + v.y * v.y;
#pragma unroll
    for (int off = 32; off > 0; off >>= 1) s += __shfl_xor(s, off, 64);
    if (lane == 0) p_sq[row] = s;
}

extern "C" void kernel_launch(void* const* d_in, const int* in_sizes, int n_in,
                              void* d_out, int out_size, void* d_ws, size_t ws_size,
                              hipStream_t stream) {
    const float* points  = (const float*)d_in[0];
    const float* values  = (const float*)d_in[1];
    const float* pointsq = (const float*)d_in[2];
    float*       out     = (float*)d_out;

    // ws layout: keys (128 KB) | p_sq (64 KB) | A2 (8 MB) | B2 (8 MB)
    const size_t OFF_KEYS = 0;
    const size_t OFF_PSQ  = 131072;
    const size_t OFF_A    = 196608;
    const size_t OFF_B    = OFF_A + (size_t)NQ * KT2 * 2;
    const size_t NEEDED   = OFF_B + (size_t)N_PTS * KT2 * 2;

    if (ws_size >= NEEDED) {
        unsigned long long* keys = (unsigned long long*)((char*)d_ws + OFF_KEYS);
        float*    p_sq = (float*)((char*)d_ws + OFF_PSQ);
        _Float16* Aq   = (_Float16*)((char*)d_ws + OFF_A);
        _Float16* Bp   = (_Float16*)((char*)d_ws + OFF_B);

        split_fused<<<QBLOCKS + PBLOCKS, 256, 0, stream>>>(pointsq, points, Aq, Bp, p_sq, keys);
        nn_mfma<<<(NQ / BM) * NCHUNK, 256, 0, stream>>>(Aq, Bp, p_sq, keys);
        gather_kernel<<<NQ / 16, 256, 0, stream>>>(keys, values, out);
    } else {
        float* p_sq = (float*)d_ws;
        psq_kernel<<<N_PTS / 4, 256, 0, stream>>>(points, p_sq);
        nn_kernel<<<NQ / QT, 256, 0, stream>>>(points, values, pointsq, p_sq, out);
    }
}

// Round 11
// 253.735 us; speedup vs baseline: 1.5406x; 1.5406x over previous
//
#include <hip/hip_runtime.h>

#define N_PTS 16384
#define DIMS  128
#define NQ    16384
#define NV    64
#define KT2   256   // [h1 | h2] layout, 128 cols each
#define BK    64
#define BM    128
#define BN    128
#define CHUNK_NT 16                // ntiles per block
#define CHUNK_N  (BN * CHUNK_NT)   // 2048 points per block
#define NCHUNK   (N_PTS / CHUNK_N) // 8

typedef __attribute__((ext_vector_type(8))) _Float16 half8;
typedef __attribute__((ext_vector_type(4))) _Float16 half4;
typedef __attribute__((ext_vector_type(4))) float    f32x4;

// ---- fused preprocessing: split both inputs to [h1|h2], p_sq for points, keys init ----
#define QBLOCKS (NQ * DIMS / 1024)
#define PBLOCKS (N_PTS * DIMS / 1024)
__global__ __launch_bounds__(256) void split_fused(const float* __restrict__ q,
                                                   const float* __restrict__ pts,
                                                   _Float16* __restrict__ Aq,
                                                   _Float16* __restrict__ Bp,
                                                   float* __restrict__ p_sq,
                                                   unsigned long long* __restrict__ keys) {
    int t = blockIdx.x * 256 + threadIdx.x;
    if (t < NQ) keys[t] = ~0ull;
    const float* src;
    _Float16* dst;
    int t2;
    bool is_p = blockIdx.x >= QBLOCKS;
    if (is_p) { t2 = t - QBLOCKS * 256; src = pts; dst = Bp; }
    else      { t2 = t;                 src = q;   dst = Aq; }
    int idx4 = t2 * 4;
    int r = idx4 >> 7, c = idx4 & 127;
    float4 x = *(const float4*)(src + idx4);
    float xs[4] = {x.x, x.y, x.z, x.w};
    half4 h1, h2;
    float s = 0.f;
#pragma unroll
    for (int j = 0; j < 4; ++j) {
        _Float16 a = (_Float16)xs[j];
        h1[j] = a;
        h2[j] = (_Float16)(xs[j] - (float)a);
        s += xs[j] * xs[j];
    }
    _Float16* o = dst + (size_t)r * KT2 + c;
    *(half4*)o = h1; *(half4*)(o + 128) = h2;
    if (is_p) {
#pragma unroll
        for (int off = 1; off < 32; off <<= 1) s += __shfl_xor(s, off, 64);
        if ((threadIdx.x & 31) == 0) p_sq[r] = s;
    }
}

__device__ __forceinline__ unsigned int f2sortable(float f) {
    unsigned int b = __float_as_uint(f);
    return (b & 0x80000000u) ? ~b : (b | 0x80000000u);
}

__device__ __forceinline__ void gload16(const _Float16* g, const _Float16* l) {
    __builtin_amdgcn_global_load_lds((const __attribute__((address_space(1))) void*)g,
                                     (__attribute__((address_space(3))) void*)l, 16, 0, 0);
}

// -------- main: Ah1 LDS-static + ah2 regs (R9 plan); B 3-slot ring, 3 barriers/ntile,
//          paired products share one B-fragment read (64 vs 80 b128/wave/ntile) --------
__global__ __launch_bounds__(256, 2) void nn_mfma(const _Float16* __restrict__ A,   // [NQ][256]
                                                  const _Float16* __restrict__ B,   // [N_PTS][256]
                                                  const float* __restrict__ p_sq,
                                                  unsigned long long* __restrict__ keys) {
    __shared__ _Float16 Ah1[2][BM * BK];   // 2 x 16 KB, block-constant
    __shared__ _Float16 Bsl[3][BN * BK];   // 3 x 16 KB rotating ring  -> total 80 KB

    const int bid   = blockIdx.x;
    const int mtile = bid >> 3;
    const int chunk = bid & 7;
    const int nbase = chunk * CHUNK_N;

    const int tid = threadIdx.x;
    const int w   = tid >> 6;
    const int l   = tid & 63;
    const int wq  = w >> 1;               // wave quadrant rows wq*64, cols wp*64
    const int wp  = w & 1;
    const int q16 = l >> 4;
    const int c16 = l & 15;

    const int srow = l >> 3;
    const int gch  = (l & 7) ^ (srow & 7);   // proven 0-conflict staging swizzle

    const _Float16* __restrict__ pa = A + (size_t)mtile * BM * KT2;
    const _Float16* __restrict__ pb = B + (size_t)nbase * KT2;

    int blane[4], ldsoff[4];
#pragma unroll
    for (int i = 0; i < 4; ++i) {
        blane[i]  = (w * 32 + i * 8 + srow) * KT2 + gch * 8;   // phase-invariant
        ldsoff[i] = (w * 32 + i * 8) * BK;
    }

    auto stageTo = [&](const _Float16* gbase, _Float16* lbase) {
#pragma unroll
        for (int i = 0; i < 4; ++i)
            gload16(gbase + blane[i], lbase + ldsoff[i]);
    };

    // prologue: Ah1 both slices + Bh1_0 of nt=0 into ring slot 0
    stageTo(pa,      &Ah1[0][0]);
    stageTo(pa + 64, &Ah1[1][0]);
    stageTo(pb,      &Bsl[0][0]);

    // Ah2 fragments -> registers, once per block (proven 116-VGPR plan)
    half8 ah2[2][2][4];   // [slice][ks][mi]
#pragma unroll
    for (int s = 0; s < 2; ++s)
#pragma unroll
        for (int ks = 0; ks < 2; ++ks)
#pragma unroll
            for (int mi = 0; mi < 4; ++mi) {
                int row = wq * 64 + mi * 16 + c16;
                ah2[s][ks][mi] = *(const half8*)(pa + (size_t)row * KT2 + 128 + s * 64 + ks * 32 + q16 * 8);
            }

    float    best[4][4];
    unsigned bpak[4][2];
#pragma unroll
    for (int mi = 0; mi < 4; ++mi) {
        best[mi][0] = best[mi][1] = best[mi][2] = best[mi][3] = 3.4e38f;
        bpak[mi][0] = bpak[mi][1] = 0;
    }

    f32x4 acc[4][4] = {};

    // dual product: A from LDS (ah) + A from regs (ar) sharing ONE B-fragment read
    auto segDual = [&](const _Float16* ah, const half8 (&ar)[2][4], const _Float16* bs) {
#pragma unroll
        for (int ks = 0; ks < 2; ++ks) {
            int slot8 = ((ks * 4 + q16) ^ (c16 & 7)) * 8;
            half8 a[4], b[4];
#pragma unroll
            for (int ni = 0; ni < 4; ++ni)
                b[ni] = *(const half8*)(bs + (wp * 64 + ni * 16 + c16) * BK + slot8);
#pragma unroll
            for (int mi = 0; mi < 4; ++mi)
                a[mi] = *(const half8*)(ah + (wq * 64 + mi * 16 + c16) * BK + slot8);
#pragma unroll
            for (int mi = 0; mi < 4; ++mi)
#pragma unroll
                for (int ni = 0; ni < 4; ++ni)
                    acc[mi][ni] = __builtin_amdgcn_mfma_f32_16x16x32_f16(a[mi], b[ni], acc[mi][ni], 0, 0, 0);
#pragma unroll
            for (int mi = 0; mi < 4; ++mi)
#pragma unroll
                for (int ni = 0; ni < 4; ++ni)
                    acc[mi][ni] = __builtin_amdgcn_mfma_f32_16x16x32_f16(ar[ks][mi], b[ni], acc[mi][ni], 0, 0, 0);
        }
    };
    // single product, A from LDS
    auto segOne = [&](const _Float16* ah, const _Float16* bs) {
#pragma unroll
        for (int ks = 0; ks < 2; ++ks) {
            int slot8 = ((ks * 4 + q16) ^ (c16 & 7)) * 8;
            half8 a[4], b[4];
#pragma unroll
            for (int ni = 0; ni < 4; ++ni)
                b[ni] = *(const half8*)(bs + (wp * 64 + ni * 16 + c16) * BK + slot8);
#pragma unroll
            for (int mi = 0; mi < 4; ++mi)
                a[mi] = *(const half8*)(ah + (wq * 64 + mi * 16 + c16) * BK + slot8);
#pragma unroll
            for (int mi = 0; mi < 4; ++mi)
#pragma unroll
                for (int ni = 0; ni < 4; ++ni)
                    acc[mi][ni] = __builtin_amdgcn_mfma_f32_16x16x32_f16(a[mi], b[ni], acc[mi][ni], 0, 0, 0);
        }
    };

    // rotating ring pointers: p0 = slice Bh1_0's slot for the current ntile
    _Float16* p0 = &Bsl[0][0];
    _Float16* p1 = &Bsl[1][0];
    _Float16* p2 = &Bsl[2][0];

#pragma unroll 1
    for (int nt = 0; nt < CHUNK_NT; ++nt) {
        const _Float16* pbn = pb + (size_t)nt * BN * KT2;

        float psq[4];
#pragma unroll
        for (int ni = 0; ni < 4; ++ni)
            psq[ni] = p_sq[nbase + nt * BN + wp * 64 + ni * 16 + c16];

        // seg0: Bh1_0 @ p0; dual products Ah1_0 (LDS) + ah2_0 (regs)
        __syncthreads();                      // drains stage of Bh1_0
        stageTo(pbn + 64, p1);                // Bh1_1 for seg1
        segDual(&Ah1[0][0], ah2[0], p0);

        // seg1: Bh1_1 @ p1; dual products Ah1_1 + ah2_1
        __syncthreads();
        stageTo(pbn + 128, p2);               // Bh2_0 for seg2
        stageTo(pbn + 192, p0);               // Bh2_1 for seg2 (p0 free after seg0)
        segDual(&Ah1[1][0], ah2[1], p1);

        // seg2: Bh2_0 @ p2 with Ah1_0; Bh2_1 @ p0 with Ah1_1
        __syncthreads();
        if (nt + 1 < CHUNK_NT)
            stageTo(pbn + BN * KT2, p1);      // next ntile's Bh1_0 (p1 free after seg1)
        segOne(&Ah1[0][0], p2);
        segOne(&Ah1[1][0], p0);

        // rotate ring: next ntile's Bh1_0 lives in p1
        _Float16* t0 = p0;
        p0 = p1; p1 = p2; p2 = t0;

        // per-ntile argmin update (registers only; candidates ascend in idx => strict <)
#pragma unroll
        for (int mi = 0; mi < 4; ++mi)
#pragma unroll
            for (int reg = 0; reg < 4; ++reg) {
                float s0 = psq[0] - 2.0f * acc[mi][0][reg];
                float s1 = psq[1] - 2.0f * acc[mi][1][reg];
                float s2 = psq[2] - 2.0f * acc[mi][2][reg];
                float s3 = psq[3] - 2.0f * acc[mi][3][reg];
                float bv = s0; int bn2 = 0;
                if (s1 < bv) { bv = s1; bn2 = 1; }
                if (s2 < bv) { bv = s2; bn2 = 2; }
                if (s3 < bv) { bv = s3; bn2 = 3; }
                bool take = bv < best[mi][reg];
                unsigned lidx = (unsigned)(nt * BN + wp * 64 + (bn2 << 4) + c16);
                unsigned sh = (reg & 1) * 16;
                unsigned cur = bpak[mi][reg >> 1];
                unsigned nw  = (cur & ~(0xFFFFu << sh)) | (lidx << sh);
                best[mi][reg]      = take ? bv : best[mi][reg];
                bpak[mi][reg >> 1] = take ? nw : cur;
            }
#pragma unroll
        for (int mi = 0; mi < 4; ++mi)
#pragma unroll
            for (int ni = 0; ni < 4; ++ni)
                acc[mi][ni] = (f32x4)(0.f);
    }

    // final: butterfly across c16 lanes, one atomic per row
#pragma unroll
    for (int mi = 0; mi < 4; ++mi)
#pragma unroll
        for (int reg = 0; reg < 4; ++reg) {
            float    bv   = best[mi][reg];
            unsigned lidx = (bpak[mi][reg >> 1] >> ((reg & 1) * 16)) & 0xFFFFu;
#pragma unroll
            for (int off = 1; off < 16; off <<= 1) {
                float    ov = __shfl_xor(bv, off, 64);
                unsigned oi = __shfl_xor((int)lidx, off, 64);
                if (ov < bv || (ov == bv && oi < lidx)) { bv = ov; lidx = oi; }
            }
            if (c16 == 0) {
                int row = mtile * BM + wq * 64 + mi * 16 + q16 * 4 + reg;
                unsigned long long key =
                    ((unsigned long long)f2sortable(bv) << 32) | (unsigned)(nbase + lidx);
                atomicMin(&keys[row], key);
            }
        }
}

// ---------------- gather ----------------
__global__ __launch_bounds__(256) void gather_kernel(const unsigned long long* __restrict__ keys,
                                                     const float* __restrict__ values,
                                                     float* __restrict__ out) {
    int tid = threadIdx.x;
    int q = blockIdx.x * 16 + (tid >> 4);
    int c = tid & 15;
    int idx = (int)(keys[q] & 0xFFFFFFFFull);
    const float4* src = (const float4*)(values + (size_t)idx * NV);
    float4*       dst = (float4*)(out + (size_t)q * NV);
    dst[c] = src[c];
}

// ================= fallback (round-1 fp32 LDS kernel) =================
#define QT 64
#define PT 64
#define LSTRIDE 132
__global__ __launch_bounds__(256, 2) void nn_kernel(const float* __restrict__ points,
                                                    const float* __restrict__ values,
                                                    const float* __restrict__ pointsq,
                                                    const float* __restrict__ p_sq,
                                                    float* __restrict__ out) {
    __shared__ float lq[QT * LSTRIDE];
    __shared__ float lp[PT * LSTRIDE];
    __shared__ float lps[PT];
    __shared__ float red_val[QT][16];
    __shared__ int   red_idx[QT][16];
    __shared__ int   nn_idx[QT];

    const int tid = threadIdx.x;
    const int tx = tid & 15, ty = tid >> 4;
    const int qbase = blockIdx.x * QT;
    {
        int ql = tid >> 2, quad = tid & 3;
        const float4* src = (const float4*)(pointsq + (size_t)(qbase + ql) * DIMS);
#pragma unroll
        for (int j = 0; j < 8; ++j)
            *(float4*)(lq + ql * LSTRIDE + (quad + 4 * j) * 4) = src[quad + 4 * j];
    }
    float minv[4]; int mini[4];
#pragma unroll
    for (int qi = 0; qi < 4; ++qi) { minv[qi] = 3.4e38f; mini[qi] = 0; }
    for (int tile = 0; tile < N_PTS / PT; ++tile) {
        __syncthreads();
        {
            int pl = tid >> 2, quad = tid & 3;
            const float4* src = (const float4*)(points + (size_t)(tile * PT + pl) * DIMS);
#pragma unroll
            for (int j = 0; j < 8; ++j)
                *(float4*)(lp + pl * LSTRIDE + (quad + 4 * j) * 4) = src[quad + 4 * j];
            if (tid < PT) lps[tid] = p_sq[tile * PT + tid];
        }
        __syncthreads();
        float accl[4][4];
#pragma unroll
        for (int qi = 0; qi < 4; ++qi)
#pragma unroll
            for (int pi = 0; pi < 4; ++pi) accl[qi][pi] = 0.f;
        for (int kc = 0; kc < DIMS / 4; ++kc) {
            float4 aq[4], ap[4];
#pragma unroll
            for (int qi = 0; qi < 4; ++qi) aq[qi] = *(const float4*)(lq + (ty + 16 * qi) * LSTRIDE + kc * 4);
#pragma unroll
            for (int pi = 0; pi < 4; ++pi) ap[pi] = *(const float4*)(lp + (tx + 16 * pi) * LSTRIDE + kc * 4);
#pragma unroll
            for (int qi = 0; qi < 4; ++qi)
#pragma unroll
                for (int pi = 0; pi < 4; ++pi) {
                    accl[qi][pi] += aq[qi].x * ap[pi].x; accl[qi][pi] += aq[qi].y * ap[pi].y;
                    accl[qi][pi] += aq[qi].z * ap[pi].z; accl[qi][pi] += aq[qi].w * ap[pi].w;
                }
        }
#pragma unroll
        for (int qi = 0; qi < 4; ++qi)
#pragma unroll
            for (int pi = 0; pi < 4; ++pi) {
                float score = lps[tx + 16 * pi] - 2.f * accl[qi][pi];
                int idx = tile * PT + tx + 16 * pi;
                if (score < minv[qi]) { minv[qi] = score; mini[qi] = idx; }
            }
    }
    __syncthreads();
#pragma unroll
    for (int qi = 0; qi < 4; ++qi) { red_val[ty + 16 * qi][tx] = minv[qi]; red_idx[ty + 16 * qi][tx] = mini[qi]; }
    __syncthreads();
    if (tid < QT) {
        float bv = red_val[tid][0]; int bi = red_idx[tid][0];
#pragma unroll
        for (int t = 1; t < 16; ++t) {
            float v = red_val[tid][t]; int i = red_idx[tid][t];
            if (v < bv || (v == bv && i < bi)) { bv = v; bi = i; }
        }
        nn_idx[tid] = bi;
    }
    __syncthreads();
    {
        int ql = tid >> 2, quad = tid & 3;
        const float4* src = (const float4*)(values + (size_t)nn_idx[ql] * NV);
        float4* dst = (float4*)(out + (size_t)(qbase + ql) * NV);
#pragma unroll
        for (int j = 0; j < 4; ++j) dst[quad * 4 + j] = src[quad * 4 + j];
    }
}

__global__ __launch_bounds__(256) void psq_kernel(const float* __restrict__ points,
                                                  float* __restrict__ p_sq) {
    int row  = blockIdx.x * 4 + (threadIdx.x >> 6);
    int lane = threadIdx.x & 63;
    float2 v = *(const float2*)(points + row * DIMS + lane * 2);
    float s = v.x * v.x + v.y * v.y;
#pragma unroll
    for (int off = 32; off > 0; off >>= 1) s += __shfl_xor(s, off, 64);
    if (lane == 0) p_sq[row] = s;
}

extern "C" void kernel_launch(void* const* d_in, const int* in_sizes, int n_in,
                              void* d_out, int out_size, void* d_ws, size_t ws_size,
                              hipStream_t stream) {
    const float* points  = (const float*)d_in[0];
    const float* values  = (const float*)d_in[1];
    const float* pointsq = (const float*)d_in[2];
    float*       out     = (float*)d_out;

    // ws layout: keys (128 KB) | p_sq (64 KB) | A2 (8 MB) | B2 (8 MB)
    const size_t OFF_KEYS = 0;
    const size_t OFF_PSQ  = 131072;
    const size_t OFF_A    = 196608;
    const size_t OFF_B    = OFF_A + (size_t)NQ * KT2 * 2;
    const size_t NEEDED   = OFF_B + (size_t)N_PTS * KT2 * 2;

    if (ws_size >= NEEDED) {
        unsigned long long* keys = (unsigned long long*)((char*)d_ws + OFF_KEYS);
        float*    p_sq = (float*)((char*)d_ws + OFF_PSQ);
        _Float16* Aq   = (_Float16*)((char*)d_ws + OFF_A);
        _Float16* Bp   = (_Float16*)((char*)d_ws + OFF_B);

        split_fused<<<QBLOCKS + PBLOCKS, 256, 0, stream>>>(pointsq, points, Aq, Bp, p_sq, keys);
        nn_mfma<<<(NQ / BM) * NCHUNK, 256, 0, stream>>>(Aq, Bp, p_sq, keys);
        gather_kernel<<<NQ / 16, 256, 0, stream>>>(keys, values, out);
    } else {
        float* p_sq = (float*)d_ws;
        psq_kernel<<<N_PTS / 4, 256, 0, stream>>>(points, p_sq);
        nn_kernel<<<NQ / QT, 256, 0, stream>>>(points, values, pointsq, p_sq, out);
    }
}